// Round 4
// baseline (8854.704 us; speedup 1.0000x reference)
//
#include <hip/hip_runtime.h>
#include <hip/hip_bf16.h>

#define NNODES 50000
#define NEDGES 800000
#define DIM 128
#define NH 8
#define HID 512
#define CHUNK 3125
#define WFTOT 347136

#define OFF_FC_W 0
#define OFF_FC_B 16384
#define OFF_AU_W 16512
#define OFF_AU_B 17536
#define OFF_AV_W 17544
#define OFF_W1   18568
#define OFF_B1   280712
#define OFF_W2   281224
#define OFF_B2   346760

// bf16 N(0,1) -> every u16 has biased exp <= ~0x81; fp32 -> low-half u16s
// ~uniform: ~43% have exp > 0x90.  flag: 1 = bf16 inputs, 0 = fp32 inputs.
__global__ __launch_bounds__(256) void detect_dtype_kernel(
    const unsigned short* __restrict__ xu, int* __restrict__ flag)
{
    __shared__ int cnt;
    if (threadIdx.x == 0) cnt = 0;
    __syncthreads();
    int c = 0;
    for (int i = threadIdx.x; i < 8192; i += 256) {
        int e = (xu[i] >> 7) & 0xFF;
        if (e > 0x90) c++;
    }
    atomicAdd(&cnt, c);
    __syncthreads();
    if (threadIdx.x == 0) flag[0] = (cnt < 100) ? 1 : 0;
}

__global__ __launch_bounds__(256) void convert_kernel(
    const void* __restrict__ in, float* __restrict__ out, int n,
    const int* __restrict__ flag)
{
    int i = blockIdx.x * 256 + threadIdx.x;
    if (i >= n) return;
    if (*flag) out[i] = __bfloat162float(((const __hip_bfloat16*)in)[i]);
    else       out[i] = ((const float*)in)[i];
}

// NT GEMM, fp32 compute. AFLAG: A read per *flag (bf16/fp32 raw input).
// OFLAG: C is d_out -> store bf16 if flag else bf16-truncated fp32; row
// offset row0 supports chunked output. ACT=1: exact gelu.
template<int AFLAG, int OFLAG, int ACT>
__global__ __launch_bounds__(256) void gemm_nt(
    const void* __restrict__ Araw, int lda,
    const float* __restrict__ B, int ldb,
    const float* __restrict__ bias,
    void* __restrict__ Craw, int ldc, int row0,
    int M, int N, int K, const int* __restrict__ flag)
{
    constexpr int BM = 64, BN = 64, BK = 32, TM = 4, TN = 4;
    __shared__ float As[BM][BK];
    __shared__ float Bs[BN][BK];

    const int t  = threadIdx.x;
    const int bm = blockIdx.y * BM;
    const int bn = blockIdx.x * BN;
    const int tx = t % (BN / TN);
    const int ty = t / (BN / TN);
    const int fl = (AFLAG || OFLAG) ? *flag : 0;

    float acc[TM][TN];
#pragma unroll
    for (int i = 0; i < TM; ++i)
#pragma unroll
        for (int j = 0; j < TN; ++j) acc[i][j] = 0.f;

    for (int k0 = 0; k0 < K; k0 += BK) {
#pragma unroll
        for (int idx = t; idx < BM * BK; idx += 256) {
            int r = idx / BK, c = idx % BK;
            int gr = bm + r;
            float v = 0.f;
            if (gr < M) {
                size_t off = (size_t)gr * lda + k0 + c;
                if (AFLAG && fl) v = __bfloat162float(((const __hip_bfloat16*)Araw)[off]);
                else             v = ((const float*)Araw)[off];
            }
            As[r][c] = v;
        }
#pragma unroll
        for (int idx = t; idx < BN * BK; idx += 256) {
            int r = idx / BK, c = idx % BK;
            Bs[r][c] = B[(size_t)(bn + r) * ldb + k0 + c];
        }
        __syncthreads();

#pragma unroll
        for (int kk = 0; kk < BK; ++kk) {
            float a[TM], b[TN];
#pragma unroll
            for (int i = 0; i < TM; ++i) a[i] = As[ty * TM + i][kk];
#pragma unroll
            for (int j = 0; j < TN; ++j) b[j] = Bs[tx * TN + j][kk];
#pragma unroll
            for (int i = 0; i < TM; ++i)
#pragma unroll
                for (int j = 0; j < TN; ++j) acc[i][j] += a[i] * b[j];
        }
        __syncthreads();
    }

#pragma unroll
    for (int i = 0; i < TM; ++i) {
        int gr = bm + ty * TM + i;
        if (gr >= M) continue;
#pragma unroll
        for (int j = 0; j < TN; ++j) {
            int gc = bn + tx * TN + j;
            float v = acc[i][j] + bias[gc];
            if (ACT == 1) v = 0.5f * v * (1.f + erff(v * 0.70710678118654752f));
            size_t off = (size_t)(row0 + gr) * ldc + gc;
            if (OFLAG) {
                if (fl) ((__hip_bfloat16*)Craw)[off] = __float2bfloat16(v);
                else    ((float*)Craw)[off] = __bfloat162float(__float2bfloat16(v));
            } else {
                ((float*)Craw)[off] = v;
            }
        }
    }
}

__global__ __launch_bounds__(256) void attn_scores_kernel(
    const float* __restrict__ cat, const float* __restrict__ wf,
    float* __restrict__ su, float* __restrict__ sv, int N)
{
    const int wave = threadIdx.x >> 6;
    const int lane = threadIdx.x & 63;
    const int n = blockIdx.x * 4 + wave;
    if (n >= N) return;

    const float h0 = cat[(size_t)n * 512 + lane];
    const float h1 = cat[(size_t)n * 512 + 64 + lane];
    const float* au_w = wf + OFF_AU_W;
    const float* av_w = wf + OFF_AV_W;

    float au[NH], av[NH];
#pragma unroll
    for (int hh = 0; hh < NH; ++hh) {
        au[hh] = h0 * au_w[hh * DIM + lane] + h1 * au_w[hh * DIM + 64 + lane];
        av[hh] = h0 * av_w[hh * DIM + lane] + h1 * av_w[hh * DIM + 64 + lane];
    }
#pragma unroll
    for (int off = 32; off >= 1; off >>= 1) {
#pragma unroll
        for (int hh = 0; hh < NH; ++hh) {
            au[hh] += __shfl_down(au[hh], off, 64);
            av[hh] += __shfl_down(av[hh], off, 64);
        }
    }
    if (lane == 0) {
#pragma unroll
        for (int hh = 0; hh < NH; ++hh) {
            su[(size_t)n * NH + hh] = au[hh] + wf[OFF_AU_B + hh];
            sv[(size_t)n * NH + hh] = av[hh];
        }
    }
}

__global__ __launch_bounds__(256) void degree_kernel(
    const int* __restrict__ src, const int* __restrict__ dst,
    float* __restrict__ in_deg, float* __restrict__ out_deg, int E)
{
    int e = blockIdx.x * 256 + threadIdx.x;
    if (e >= E) return;
    atomicAdd(&in_deg[dst[e]], 1.f);
    atomicAdd(&out_deg[src[e]], 1.f);
}

__global__ __launch_bounds__(256) void edge_softmax_den_kernel(
    const int* __restrict__ src, const int* __restrict__ dst,
    const float* __restrict__ su, const float* __restrict__ sv,
    float* __restrict__ den, int E)
{
    int gid = blockIdx.x * 256 + threadIdx.x;
    if (gid >= E * NH) return;
    int e = gid >> 3, hh = gid & 7;
    int s = src[e], d = dst[e];
    float sc = su[(size_t)s * NH + hh] + sv[(size_t)d * NH + hh];
    sc = sc < 0.f ? 0.2f * sc : sc;
    atomicAdd(&den[(size_t)d * NH + hh], expf(sc));
}

__global__ __launch_bounds__(256) void aggregate_kernel(
    const int* __restrict__ src, const int* __restrict__ dst,
    const float* __restrict__ su, const float* __restrict__ sv,
    const float* __restrict__ den, const float* __restrict__ out_deg,
    float* __restrict__ cat, int E)
{
    int gid = blockIdx.x * 256 + threadIdx.x;
    if (gid >= E * DIM) return;
    int e = gid >> 7, d = gid & 127;
    int s = src[e], dd = dst[e];
    float hs = cat[(size_t)s * 512 + d];
    int hh = d & 7;
    float sc = su[(size_t)s * NH + hh] + sv[(size_t)dd * NH + hh];
    sc = sc < 0.f ? 0.2f * sc : sc;
    float p = expf(sc) / den[(size_t)dd * NH + hh];
    float norm = rsqrtf(out_deg[s] * out_deg[dd]);
    float* crow = cat + (size_t)dd * 512;
    atomicAdd(crow + 128 + d, hs * p);
    atomicAdd(crow + 256 + d, hs);
    atomicAdd(crow + 384 + d, hs * norm);
}

__global__ __launch_bounds__(256) void scale_mean_kernel(
    float* __restrict__ cat, const float* __restrict__ in_deg, int N)
{
    int gid = blockIdx.x * 256 + threadIdx.x;
    if (gid >= N * DIM) return;
    int n = gid >> 7, d = gid & 127;
    cat[(size_t)n * 512 + 256 + d] *= 1.f / fmaxf(in_deg[n], 1.f);
}

extern "C" void kernel_launch(void* const* d_in, const int* in_sizes, int n_in,
                              void* d_out, int out_size, void* d_ws, size_t ws_size,
                              hipStream_t stream)
{
    const void* x   = d_in[0];
    const int*  src = (const int*)d_in[1];
    const int*  dst = (const int*)d_in[2];
    const int N = NNODES, E = NEDGES;

    // ws layout (floats) — ~115.4 MB total
    int*   flag    = (int*)d_ws;
    float* wf      = (float*)d_ws + 64;
    float* cat     = wf + WFTOT;                 // N*512
    float* den     = cat + (size_t)N * 512;      // N*8
    float* in_deg  = den + (size_t)N * NH;       // N
    float* out_deg = in_deg + N;                 // N
    float* su      = out_deg + N;                // N*8
    float* sv      = su + (size_t)N * NH;        // N*8
    float* fbuf    = sv + (size_t)N * NH;        // CHUNK*512

    detect_dtype_kernel<<<1, 256, 0, stream>>>((const unsigned short*)x, flag);

    const struct { int idx; int off; int n; } cv[9] = {
        {3, OFF_FC_W, 16384}, {4, OFF_FC_B, 128},  {5, OFF_AU_W, 1024},
        {6, OFF_AU_B, 8},     {7, OFF_AV_W, 1024}, {8, OFF_W1, 262144},
        {9, OFF_B1, 512},     {10, OFF_W2, 65536}, {11, OFF_B2, 128}};
    for (int i = 0; i < 9; ++i)
        convert_kernel<<<(cv[i].n + 255) / 256, 256, 0, stream>>>(
            d_in[cv[i].idx], wf + cv[i].off, cv[i].n, flag);

    hipMemsetAsync(cat, 0, (size_t)N * 512 * sizeof(float), stream);
    hipMemsetAsync(den, 0, (size_t)N * (NH + 2) * sizeof(float), stream);

    {   // 1) h = x @ fc_w.T + fc_b -> cat[:, :128]
        dim3 g(DIM / 64, (N + 63) / 64);
        gemm_nt<1, 0, 0><<<g, 256, 0, stream>>>(x, DIM, wf + OFF_FC_W, DIM,
                                                wf + OFF_FC_B, cat, 512, 0,
                                                N, DIM, DIM, flag);
    }
    attn_scores_kernel<<<(N + 3) / 4, 256, 0, stream>>>(cat, wf, su, sv, N);
    degree_kernel<<<(E + 255) / 256, 256, 0, stream>>>(src, dst, in_deg, out_deg, E);
    edge_softmax_den_kernel<<<(E * NH + 255) / 256, 256, 0, stream>>>(src, dst, su, sv, den, E);
    aggregate_kernel<<<(E * DIM) / 256, 256, 0, stream>>>(src, dst, su, sv, den, out_deg, cat, E);
    scale_mean_kernel<<<(N * DIM + 255) / 256, 256, 0, stream>>>(cat, in_deg, N);

    for (int c = 0; c < 16; ++c) {
        const float* catc = cat + (size_t)c * CHUNK * 512;
        {   // f_chunk = gelu(cat_chunk @ w1.T + b1) -> fbuf (fp32)
            dim3 g(HID / 64, (CHUNK + 63) / 64);
            gemm_nt<0, 0, 1><<<g, 256, 0, stream>>>(catc, 512, wf + OFF_W1, 512,
                                                    wf + OFF_B1, fbuf, HID, 0,
                                                    CHUNK, HID, 512, flag);
        }
        {   // out_chunk = f_chunk @ w2.T + b2 -> d_out rows [c*CHUNK ...)
            dim3 g(DIM / 64, (CHUNK + 63) / 64);
            gemm_nt<0, 1, 0><<<g, 256, 0, stream>>>(fbuf, HID, wf + OFF_W2, 512,
                                                    wf + OFF_B2, d_out, DIM,
                                                    c * CHUNK, CHUNK, DIM, 512, flag);
        }
    }
}

// Round 5
// 1758.755 us; speedup vs baseline: 5.0346x; 5.0346x over previous
//
#include <hip/hip_runtime.h>
#include <hip/hip_bf16.h>

#define NNODES 50000
#define NEDGES 800000
#define DIM 128
#define NH 8
#define HID 512
#define CH 6250              // FFN row chunk (N/8)

typedef unsigned short ushort_t;
typedef __attribute__((ext_vector_type(8))) short bf16x8;
typedef __attribute__((ext_vector_type(4))) float f32x4;

// ---------------------------------------------------------------------------
// fp32 -> bf16 (RNE) elementwise
// ---------------------------------------------------------------------------
__global__ __launch_bounds__(256) void f32_to_bf16_kernel(
    const float* __restrict__ in, ushort_t* __restrict__ out, int n)
{
    int i = blockIdx.x * 256 + threadIdx.x;
    if (i >= n) return;
    ((__hip_bfloat16*)out)[i] = __float2bfloat16(in[i]);
}

// ---------------------------------------------------------------------------
// MFMA NT GEMM: C[m,n] = act(sum_k A[m,k]*B[n,k] + bias[n])
// A,B bf16 row-major; bias fp32; C bf16 (OUTF32=0) or fp32 (OUTF32=1).
// BM=BN=128, BK=64; 4 waves in 2x2, each wave 64x64 via 4x4 mfma 16x16x32.
// Ncols (grid.x*128) must be a multiple of 128 and <= rows of B.
// In-place A==C is safe when grid.x==1 (each block reads only its own rows,
// all reads precede the epilogue stores).
// ---------------------------------------------------------------------------
template<int OUTF32, int ACT>
__global__ __launch_bounds__(256) void gemm_mfma(
    const ushort_t* A, int lda,
    const ushort_t* __restrict__ B, int ldb,
    const float* __restrict__ bias,
    void* C, int ldc, int row0,
    int M, int K)
{
    constexpr int BM = 128, BN = 128, BK = 64, PAD = 8;
    __shared__ ushort_t As[BM][BK + PAD];
    __shared__ ushort_t Bs[BN][BK + PAD];

    const int t    = threadIdx.x;
    const int bm   = blockIdx.y * BM;
    const int bn   = blockIdx.x * BN;
    const int wid  = t >> 6, lane = t & 63;
    const int wrow = wid >> 1, wcol = wid & 1;
    const int qd   = lane >> 4, l16 = lane & 15;

    f32x4 acc[4][4];
#pragma unroll
    for (int i = 0; i < 4; ++i)
#pragma unroll
        for (int j = 0; j < 4; ++j) acc[i][j] = (f32x4){0.f, 0.f, 0.f, 0.f};

    for (int k0 = 0; k0 < K; k0 += BK) {
        // stage A tile: 128x64 ushorts = 1024 x 16B vectors, 4 per thread
#pragma unroll
        for (int i = 0; i < 4; ++i) {
            int v = t + i * 256;
            int r = v >> 3, c8 = (v & 7) * 8;
            uint4 val = make_uint4(0u, 0u, 0u, 0u);
            int gr = bm + r;
            if (gr < M) val = *(const uint4*)(A + (size_t)gr * lda + k0 + c8);
            *(uint4*)(&As[r][c8]) = val;
        }
        // stage B tile (no row guard: B has >= bn+128 rows by construction)
#pragma unroll
        for (int i = 0; i < 4; ++i) {
            int v = t + i * 256;
            int r = v >> 3, c8 = (v & 7) * 8;
            *(uint4*)(&Bs[r][c8]) = *(const uint4*)(B + (size_t)(bn + r) * ldb + k0 + c8);
        }
        __syncthreads();

#pragma unroll
        for (int ks = 0; ks < 2; ++ks) {
            bf16x8 af[4], bfr[4];
#pragma unroll
            for (int mi = 0; mi < 4; ++mi)
                af[mi] = *(const bf16x8*)(&As[wrow * 64 + mi * 16 + l16][ks * 32 + qd * 8]);
#pragma unroll
            for (int ni = 0; ni < 4; ++ni)
                bfr[ni] = *(const bf16x8*)(&Bs[wcol * 64 + ni * 16 + l16][ks * 32 + qd * 8]);
#pragma unroll
            for (int mi = 0; mi < 4; ++mi)
#pragma unroll
                for (int ni = 0; ni < 4; ++ni)
                    acc[mi][ni] = __builtin_amdgcn_mfma_f32_16x16x32_bf16(
                        af[mi], bfr[ni], acc[mi][ni], 0, 0, 0);
        }
        __syncthreads();
    }

    // epilogue: C/D layout col=lane&15, row=(lane>>4)*4+reg  [m89/m91]
#pragma unroll
    for (int mi = 0; mi < 4; ++mi) {
#pragma unroll
        for (int r = 0; r < 4; ++r) {
            int lrow = wrow * 64 + mi * 16 + qd * 4 + r;
            int grow = bm + lrow;
            if (grow >= M) continue;
#pragma unroll
            for (int ni = 0; ni < 4; ++ni) {
                int gc = bn + wcol * 64 + ni * 16 + l16;
                float v = acc[mi][ni][r] + bias[gc];
                if (ACT == 1) v = 0.5f * v * (1.f + erff(v * 0.70710678118654752f));
                size_t off = (size_t)(row0 + grow) * ldc + gc;
                if (OUTF32) ((float*)C)[off] = v;
                else ((__hip_bfloat16*)C)[off] = __float2bfloat16(v);
            }
        }
    }
}

// ---------------------------------------------------------------------------
// su/sv: one wave per node, h read from hb (bf16).
// ---------------------------------------------------------------------------
__global__ __launch_bounds__(256) void attn_scores_kernel(
    const ushort_t* __restrict__ hb,
    const float* __restrict__ au_w, const float* __restrict__ au_b,
    const float* __restrict__ av_w,
    float* __restrict__ su, float* __restrict__ sv, int N)
{
    const int wave = threadIdx.x >> 6;
    const int lane = threadIdx.x & 63;
    const int n = blockIdx.x * 4 + wave;
    if (n >= N) return;

    const float h0 = __bfloat162float(((const __hip_bfloat16*)hb)[(size_t)n * DIM + lane]);
    const float h1 = __bfloat162float(((const __hip_bfloat16*)hb)[(size_t)n * DIM + 64 + lane]);

    float au[NH], av[NH];
#pragma unroll
    for (int hh = 0; hh < NH; ++hh) {
        au[hh] = h0 * au_w[hh * DIM + lane] + h1 * au_w[hh * DIM + 64 + lane];
        av[hh] = h0 * av_w[hh * DIM + lane] + h1 * av_w[hh * DIM + 64 + lane];
    }
#pragma unroll
    for (int off = 32; off >= 1; off >>= 1) {
#pragma unroll
        for (int hh = 0; hh < NH; ++hh) {
            au[hh] += __shfl_down(au[hh], off, 64);
            av[hh] += __shfl_down(av[hh], off, 64);
        }
    }
    if (lane == 0) {
#pragma unroll
        for (int hh = 0; hh < NH; ++hh) {
            su[(size_t)n * NH + hh] = au[hh] + au_b[hh];
            sv[(size_t)n * NH + hh] = av[hh];
        }
    }
}

// ---------------------------------------------------------------------------
__global__ __launch_bounds__(256) void degree_kernel(
    const int* __restrict__ src, const int* __restrict__ dst,
    float* __restrict__ in_deg, float* __restrict__ out_deg, int E)
{
    int e = blockIdx.x * 256 + threadIdx.x;
    if (e >= E) return;
    unsafeAtomicAdd(&in_deg[dst[e]], 1.f);
    unsafeAtomicAdd(&out_deg[src[e]], 1.f);
}

__global__ __launch_bounds__(256) void edge_softmax_den_kernel(
    const int* __restrict__ src, const int* __restrict__ dst,
    const float* __restrict__ su, const float* __restrict__ sv,
    float* __restrict__ den, int E)
{
    int gid = blockIdx.x * 256 + threadIdx.x;
    if (gid >= E * NH) return;
    int e = gid >> 3, hh = gid & 7;
    int s = src[e], d = dst[e];
    float sc = su[(size_t)s * NH + hh] + sv[(size_t)d * NH + hh];
    sc = sc < 0.f ? 0.2f * sc : sc;
    unsafeAtomicAdd(&den[(size_t)d * NH + hh], expf(sc));
}

// One thread per (edge, dim): three scatter-adds into agg[N,384] = [msg|msg2|msg3]
__global__ __launch_bounds__(256) void aggregate_kernel(
    const int* __restrict__ src, const int* __restrict__ dst,
    const ushort_t* __restrict__ hb,
    const float* __restrict__ su, const float* __restrict__ sv,
    const float* __restrict__ den, const float* __restrict__ out_deg,
    float* __restrict__ agg, int E)
{
    int gid = blockIdx.x * 256 + threadIdx.x;
    if (gid >= E * DIM) return;
    int e = gid >> 7, d = gid & 127;
    int s = src[e], dd = dst[e];
    float hs = __bfloat162float(((const __hip_bfloat16*)hb)[(size_t)s * DIM + d]);
    int hh = d & 7;
    float sc = su[(size_t)s * NH + hh] + sv[(size_t)dd * NH + hh];
    sc = sc < 0.f ? 0.2f * sc : sc;
    float p = expf(sc) / den[(size_t)dd * NH + hh];
    float norm = rsqrtf(out_deg[s] * out_deg[dd]);
    float* row = agg + (size_t)dd * 384;
    unsafeAtomicAdd(row + d, hs * p);
    unsafeAtomicAdd(row + 128 + d, hs);
    unsafeAtomicAdd(row + 256 + d, hs * norm);
}

// ---------------------------------------------------------------------------
// catb_c[r, 0:128] = hb[row]; [128:512] = bf16(agg[row]) with msg2 scaled by
// 1/max(in_deg,1).  row = c0 + r.
// ---------------------------------------------------------------------------
__global__ __launch_bounds__(256) void assemble_cat_kernel(
    const ushort_t* __restrict__ hb, const float* __restrict__ agg,
    const float* __restrict__ in_deg, ushort_t* __restrict__ catb, int c0)
{
    int gid = blockIdx.x * 256 + threadIdx.x;
    if (gid >= CH * 512) return;
    int r = gid >> 9, col = gid & 511;
    int row = c0 + r;
    if (col < 128) {
        catb[(size_t)r * 512 + col] = hb[(size_t)row * DIM + col];
    } else {
        float a = agg[(size_t)row * 384 + (col - 128)];
        if (col >= 256 && col < 384) a *= 1.f / fmaxf(in_deg[row], 1.f);
        ((__hip_bfloat16*)catb)[(size_t)r * 512 + col] = __float2bfloat16(a);
    }
}

// ---------------------------------------------------------------------------
extern "C" void kernel_launch(void* const* d_in, const int* in_sizes, int n_in,
                              void* d_out, int out_size, void* d_ws, size_t ws_size,
                              hipStream_t stream)
{
    const float* x    = (const float*)d_in[0];
    const int*   src  = (const int*)d_in[1];
    const int*   dst  = (const int*)d_in[2];
    const float* fc_w = (const float*)d_in[3];
    const float* fc_b = (const float*)d_in[4];
    const float* au_w = (const float*)d_in[5];
    const float* au_b = (const float*)d_in[6];
    const float* av_w = (const float*)d_in[7];
    const float* w1   = (const float*)d_in[8];
    const float* b1   = (const float*)d_in[9];
    const float* w2   = (const float*)d_in[10];
    const float* b2   = (const float*)d_in[11];
    float* out = (float*)d_out;

    const int N = NNODES, E = NEDGES;

    // ws layout — ~108.3 MB total, all 16B-aligned
    char* w = (char*)d_ws;
    ushort_t* fc_wb = (ushort_t*)w;  w += (size_t)DIM * DIM * 2;       // 32 KB
    ushort_t* w1b   = (ushort_t*)w;  w += (size_t)HID * 512 * 2;       // 512 KB
    ushort_t* w2b   = (ushort_t*)w;  w += (size_t)DIM * HID * 2;       // 128 KB
    ushort_t* hb    = (ushort_t*)w;  w += (size_t)N * DIM * 2;         // 12.8 MB
    float* agg      = (float*)w;     w += (size_t)N * 384 * 4;         // 76.8 MB
    float* den      = (float*)w;     w += (size_t)N * NH * 4;          // 1.6 MB
    float* in_deg   = (float*)w;     w += (size_t)N * 4;
    float* out_deg  = (float*)w;     w += (size_t)N * 4;
    float* su       = (float*)w;     w += (size_t)N * NH * 4;
    float* sv       = (float*)w;     w += (size_t)N * NH * 4;
    ushort_t* catb  = (ushort_t*)w;  w += (size_t)CH * 512 * 2;        // 6.4 MB
    ushort_t* fbuf  = (ushort_t*)w;  w += (size_t)CH * 512 * 2;        // 6.4 MB

    // zero the atomic accumulators (agg..out_deg contiguous)
    hipMemsetAsync(agg, 0, (size_t)N * (384 + NH + 2) * sizeof(float), stream);

    // weight + x conversion to bf16
    f32_to_bf16_kernel<<<(DIM * DIM + 255) / 256, 256, 0, stream>>>(fc_w, fc_wb, DIM * DIM);
    f32_to_bf16_kernel<<<(HID * 512 + 255) / 256, 256, 0, stream>>>(w1, w1b, HID * 512);
    f32_to_bf16_kernel<<<(DIM * HID + 255) / 256, 256, 0, stream>>>(w2, w2b, DIM * HID);
    f32_to_bf16_kernel<<<(N * DIM + 255) / 256, 256, 0, stream>>>(x, hb, N * DIM);

    // 1) h = x @ fc_w.T + fc_b  (MFMA, in-place hb: grid.x==1 so safe)
    {
        dim3 g(1, (N + 127) / 128);
        gemm_mfma<0, 0><<<g, 256, 0, stream>>>(hb, DIM, fc_wb, DIM, fc_b,
                                               hb, DIM, 0, N, DIM);
    }
    // 2) su / sv
    attn_scores_kernel<<<(N + 3) / 4, 256, 0, stream>>>(hb, au_w, au_b, av_w, su, sv, N);
    // 3) degrees
    degree_kernel<<<(E + 255) / 256, 256, 0, stream>>>(src, dst, in_deg, out_deg, E);
    // 4) softmax denominator
    edge_softmax_den_kernel<<<(E * NH + 255) / 256, 256, 0, stream>>>(src, dst, su, sv, den, E);
    // 5) three scatter aggregations into agg
    aggregate_kernel<<<(E * DIM) / 256, 256, 0, stream>>>(src, dst, hb, su, sv, den, out_deg, agg, E);

    // 6) FFN per chunk: assemble cat (bf16) -> f = gelu(cat@w1.T+b1) -> out
    for (int c = 0; c < N / CH; ++c) {
        int c0 = c * CH;
        assemble_cat_kernel<<<(CH * 512 + 255) / 256, 256, 0, stream>>>(hb, agg, in_deg, catb, c0);
        {
            dim3 g(HID / 128, (CH + 127) / 128);
            gemm_mfma<0, 1><<<g, 256, 0, stream>>>(catb, 512, w1b, 512, b1,
                                                   fbuf, HID, 0, CH, 512);
        }
        {
            dim3 g(DIM / 128, (CH + 127) / 128);
            gemm_mfma<1, 0><<<g, 256, 0, stream>>>(fbuf, HID, w2b, HID, b2,
                                                   out, DIM, c0, CH, 512);
        }
    }
}

// Round 7
// 716.601 us; speedup vs baseline: 12.3565x; 2.4543x over previous
//
#include <hip/hip_runtime.h>
#include <hip/hip_bf16.h>

#define NNODES 50000
#define NEDGES 800000
#define DIM 128
#define NH 8
#define HID 512
#define CH 12500             // FFN row chunk (N/4)

typedef unsigned short ushort_t;
typedef __attribute__((ext_vector_type(8))) short bf16x8;
typedef __attribute__((ext_vector_type(4))) float f32x4;

// ---------------------------------------------------------------------------
__global__ __launch_bounds__(256) void f32_to_bf16_kernel(
    const float* __restrict__ in, ushort_t* __restrict__ out, int n)
{
    int i = blockIdx.x * 256 + threadIdx.x;
    if (i >= n) return;
    ((__hip_bfloat16*)out)[i] = __float2bfloat16(in[i]);
}

// ---------------------------------------------------------------------------
// MFMA NT GEMM (verified r5): C = act(A@B^T + bias)
// ---------------------------------------------------------------------------
template<int OUTF32, int ACT>
__global__ __launch_bounds__(256) void gemm_mfma(
    const ushort_t* A, int lda,
    const ushort_t* __restrict__ B, int ldb,
    const float* __restrict__ bias,
    void* C, int ldc, int row0,
    int M, int K)
{
    constexpr int BM = 128, BN = 128, BK = 64, PAD = 8;
    __shared__ ushort_t As[BM][BK + PAD];
    __shared__ ushort_t Bs[BN][BK + PAD];

    const int t    = threadIdx.x;
    const int bm   = blockIdx.y * BM;
    const int bn   = blockIdx.x * BN;
    const int wid  = t >> 6, lane = t & 63;
    const int wrow = wid >> 1, wcol = wid & 1;
    const int qd   = lane >> 4, l16 = lane & 15;

    f32x4 acc[4][4];
#pragma unroll
    for (int i = 0; i < 4; ++i)
#pragma unroll
        for (int j = 0; j < 4; ++j) acc[i][j] = (f32x4){0.f, 0.f, 0.f, 0.f};

    for (int k0 = 0; k0 < K; k0 += BK) {
#pragma unroll
        for (int i = 0; i < 4; ++i) {
            int v = t + i * 256;
            int r = v >> 3, c8 = (v & 7) * 8;
            uint4 val = make_uint4(0u, 0u, 0u, 0u);
            int gr = bm + r;
            if (gr < M) val = *(const uint4*)(A + (size_t)gr * lda + k0 + c8);
            *(uint4*)(&As[r][c8]) = val;
        }
#pragma unroll
        for (int i = 0; i < 4; ++i) {
            int v = t + i * 256;
            int r = v >> 3, c8 = (v & 7) * 8;
            *(uint4*)(&Bs[r][c8]) = *(const uint4*)(B + (size_t)(bn + r) * ldb + k0 + c8);
        }
        __syncthreads();

#pragma unroll
        for (int ks = 0; ks < 2; ++ks) {
            bf16x8 af[4], bfr[4];
#pragma unroll
            for (int mi = 0; mi < 4; ++mi)
                af[mi] = *(const bf16x8*)(&As[wrow * 64 + mi * 16 + l16][ks * 32 + qd * 8]);
#pragma unroll
            for (int ni = 0; ni < 4; ++ni)
                bfr[ni] = *(const bf16x8*)(&Bs[wcol * 64 + ni * 16 + l16][ks * 32 + qd * 8]);
#pragma unroll
            for (int mi = 0; mi < 4; ++mi)
#pragma unroll
                for (int ni = 0; ni < 4; ++ni)
                    acc[mi][ni] = __builtin_amdgcn_mfma_f32_16x16x32_bf16(
                        af[mi], bfr[ni], acc[mi][ni], 0, 0, 0);
        }
        __syncthreads();
    }

#pragma unroll
    for (int mi = 0; mi < 4; ++mi) {
#pragma unroll
        for (int r = 0; r < 4; ++r) {
            int lrow = wrow * 64 + mi * 16 + qd * 4 + r;
            int grow = bm + lrow;
            if (grow >= M) continue;
#pragma unroll
            for (int ni = 0; ni < 4; ++ni) {
                int gc = bn + wcol * 64 + ni * 16 + l16;
                float v = acc[mi][ni][r] + bias[gc];
                if (ACT == 1) v = 0.5f * v * (1.f + erff(v * 0.70710678118654752f));
                size_t off = (size_t)(row0 + grow) * ldc + gc;
                if (OUTF32) ((float*)C)[off] = v;
                else ((__hip_bfloat16*)C)[off] = __float2bfloat16(v);
            }
        }
    }
}

// ---------------------------------------------------------------------------
__global__ __launch_bounds__(256) void attn_scores_kernel(
    const ushort_t* __restrict__ hb,
    const float* __restrict__ au_w, const float* __restrict__ au_b,
    const float* __restrict__ av_w,
    float* __restrict__ su, float* __restrict__ sv, int N)
{
    const int wave = threadIdx.x >> 6;
    const int lane = threadIdx.x & 63;
    const int n = blockIdx.x * 4 + wave;
    if (n >= N) return;

    const float h0 = __bfloat162float(((const __hip_bfloat16*)hb)[(size_t)n * DIM + lane]);
    const float h1 = __bfloat162float(((const __hip_bfloat16*)hb)[(size_t)n * DIM + 64 + lane]);

    float au[NH], av[NH];
#pragma unroll
    for (int hh = 0; hh < NH; ++hh) {
        au[hh] = h0 * au_w[hh * DIM + lane] + h1 * au_w[hh * DIM + 64 + lane];
        av[hh] = h0 * av_w[hh * DIM + lane] + h1 * av_w[hh * DIM + 64 + lane];
    }
#pragma unroll
    for (int off = 32; off >= 1; off >>= 1) {
#pragma unroll
        for (int hh = 0; hh < NH; ++hh) {
            au[hh] += __shfl_down(au[hh], off, 64);
            av[hh] += __shfl_down(av[hh], off, 64);
        }
    }
    if (lane == 0) {
#pragma unroll
        for (int hh = 0; hh < NH; ++hh) {
            su[(size_t)n * NH + hh] = au[hh] + au_b[hh];
            sv[(size_t)n * NH + hh] = av[hh];
        }
    }
}

// ---------------------------------------------------------------------------
// CSR build: count (+float out_deg), single-block scan, fill.
// ---------------------------------------------------------------------------
__global__ __launch_bounds__(256) void degree_count_kernel(
    const int* __restrict__ src, const int* __restrict__ dst,
    float* __restrict__ out_deg, int* __restrict__ in_cnt, int E)
{
    int e = blockIdx.x * 256 + threadIdx.x;
    if (e >= E) return;
    unsafeAtomicAdd(&out_deg[src[e]], 1.f);
    atomicAdd(&in_cnt[dst[e]], 1);
}

__global__ __launch_bounds__(1024) void scan_kernel(
    const int* __restrict__ cnt, int* __restrict__ rowstart)
{
    __shared__ int ssum[1024];
    const int tid = threadIdx.x;
    const int C = (NNODES + 1023) / 1024;   // 49
    int base = tid * C;
    int s = 0;
    for (int i = 0; i < C; ++i) {
        int idx = base + i;
        if (idx < NNODES) s += cnt[idx];
    }
    ssum[tid] = s;
    __syncthreads();
    for (int off = 1; off < 1024; off <<= 1) {
        int v = (tid >= off) ? ssum[tid - off] : 0;
        __syncthreads();
        ssum[tid] += v;
        __syncthreads();
    }
    int run = (tid == 0) ? 0 : ssum[tid - 1];
    for (int i = 0; i < C; ++i) {
        int idx = base + i;
        if (idx < NNODES) { rowstart[idx] = run; run += cnt[idx]; }
    }
    if (tid == 0) rowstart[NNODES] = NEDGES;
}

__global__ __launch_bounds__(256) void fill_csr_kernel(
    const int* __restrict__ src, const int* __restrict__ dst,
    const int* __restrict__ rowstart, int* __restrict__ cursor,
    int* __restrict__ esrc, int E)
{
    int e = blockIdx.x * 256 + threadIdx.x;
    if (e >= E) return;
    int d = dst[e];
    int pos = rowstart[d] + atomicAdd(&cursor[d], 1);
    esrc[pos] = src[e];
}

// ---------------------------------------------------------------------------
// Gather-aggregate: one wave per dst node. Lane owns dims {lane, lane+64},
// both mapping to head hh=lane&7. No atomics; writes the full bf16 cat row:
// cat[n] = [h | msg | msg2 | msg3].
// ---------------------------------------------------------------------------
__global__ __launch_bounds__(256) void gather_aggregate_kernel(
    const int* __restrict__ rowstart, const int* __restrict__ esrc,
    const ushort_t* __restrict__ hb,
    const float* __restrict__ su, const float* __restrict__ sv,
    const float* __restrict__ out_deg,
    ushort_t* __restrict__ cat, int N)
{
    const int wave = threadIdx.x >> 6;
    const int lane = threadIdx.x & 63;
    const int n = blockIdx.x * 4 + wave;
    if (n >= N) return;

    const int e0 = rowstart[n], e1 = rowstart[n + 1];
    const int deg = e1 - e0;
    const int hh = lane & 7;
    const float svh = sv[(size_t)n * NH + hh];
    const float od_d = out_deg[n];

    // pass A: den for head hh (8 edge-groups in parallel, reduce over groups)
    float den = 0.f;
    for (int j = lane >> 3; j < deg; j += 8) {
        int s = esrc[e0 + j];
        float sc = su[(size_t)s * NH + hh] + svh;
        sc = sc < 0.f ? 0.2f * sc : sc;
        den += expf(sc);
    }
    den += __shfl_xor(den, 8, 64);
    den += __shfl_xor(den, 16, 64);
    den += __shfl_xor(den, 32, 64);
    float rden = (den > 0.f) ? 1.f / den : 0.f;

    // pass B: accumulate all three messages for dims lane and lane+64
    float m0 = 0.f, m1 = 0.f, s0 = 0.f, s1 = 0.f, n0 = 0.f, n1 = 0.f;
    for (int j = 0; j < deg; ++j) {
        int s = esrc[e0 + j];
        float sc = su[(size_t)s * NH + hh] + svh;
        sc = sc < 0.f ? 0.2f * sc : sc;
        float p = expf(sc) * rden;
        float norm = rsqrtf(out_deg[s] * od_d);
        float hs0 = __bfloat162float(((const __hip_bfloat16*)hb)[(size_t)s * DIM + lane]);
        float hs1 = __bfloat162float(((const __hip_bfloat16*)hb)[(size_t)s * DIM + 64 + lane]);
        m0 += hs0 * p;    m1 += hs1 * p;
        s0 += hs0;        s1 += hs1;
        n0 += hs0 * norm; n1 += hs1 * norm;
    }
    float inv = 1.f / fmaxf((float)deg, 1.f);

    __hip_bfloat16* row = (__hip_bfloat16*)cat + (size_t)n * 512;
    row[lane]       = ((const __hip_bfloat16*)hb)[(size_t)n * DIM + lane];
    row[64 + lane]  = ((const __hip_bfloat16*)hb)[(size_t)n * DIM + 64 + lane];
    row[128 + lane] = __float2bfloat16(m0);
    row[192 + lane] = __float2bfloat16(m1);
    row[256 + lane] = __float2bfloat16(s0 * inv);
    row[320 + lane] = __float2bfloat16(s1 * inv);
    row[384 + lane] = __float2bfloat16(n0);
    row[448 + lane] = __float2bfloat16(n1);
}

// ---------------------------------------------------------------------------
extern "C" void kernel_launch(void* const* d_in, const int* in_sizes, int n_in,
                              void* d_out, int out_size, void* d_ws, size_t ws_size,
                              hipStream_t stream)
{
    const float* x    = (const float*)d_in[0];
    const int*   src  = (const int*)d_in[1];
    const int*   dst  = (const int*)d_in[2];
    const float* fc_w = (const float*)d_in[3];
    const float* fc_b = (const float*)d_in[4];
    const float* au_w = (const float*)d_in[5];
    const float* au_b = (const float*)d_in[6];
    const float* av_w = (const float*)d_in[7];
    const float* w1   = (const float*)d_in[8];
    const float* b1   = (const float*)d_in[9];
    const float* w2   = (const float*)d_in[10];
    const float* b2   = (const float*)d_in[11];
    float* out = (float*)d_out;

    const int N = NNODES, E = NEDGES;

    // ws layout, ~85 MB total, all 16B aligned
    // (NOTE: no trailing backslashes in comments — r6's compile failure was a
    //  line-continuation splicing the in_cnt declaration into a comment.)
    char* w = (char*)d_ws;
    ushort_t* fc_wb = (ushort_t*)w;  w += (size_t)DIM * DIM * 2;
    ushort_t* w1b   = (ushort_t*)w;  w += (size_t)HID * 512 * 2;
    ushort_t* w2b   = (ushort_t*)w;  w += (size_t)DIM * HID * 2;
    ushort_t* hb    = (ushort_t*)w;  w += (size_t)N * DIM * 2;       // 12.8 MB
    ushort_t* cat   = (ushort_t*)w;  w += (size_t)N * 512 * 2;       // 51.2 MB
    float* su       = (float*)w;     w += (size_t)N * NH * 4;
    float* sv       = (float*)w;     w += (size_t)N * NH * 4;
    float* out_deg  = (float*)w;     w += (size_t)N * 4;             // zeroed (1/3)
    int*   in_cnt   = (int*)w;       w += (size_t)N * 4;             // zeroed (2/3)
    int*   cursor   = (int*)w;       w += (size_t)N * 4;             // zeroed (3/3)
    int*   rowstart = (int*)w;       w += (size_t)(N + 16) * 4;
    int*   esrc     = (int*)w;       w += (size_t)E * 4;             // 3.2 MB
    ushort_t* fbuf  = (ushort_t*)w;  w += (size_t)CH * 512 * 2;      // 12.8 MB

    (void)hipMemsetAsync(out_deg, 0, (size_t)N * 3 * 4, stream);

    // convert weights + x to bf16
    f32_to_bf16_kernel<<<(DIM * DIM + 255) / 256, 256, 0, stream>>>(fc_w, fc_wb, DIM * DIM);
    f32_to_bf16_kernel<<<(HID * 512 + 255) / 256, 256, 0, stream>>>(w1, w1b, HID * 512);
    f32_to_bf16_kernel<<<(DIM * HID + 255) / 256, 256, 0, stream>>>(w2, w2b, DIM * HID);
    f32_to_bf16_kernel<<<(N * DIM + 255) / 256, 256, 0, stream>>>(x, hb, N * DIM);

    // 1) h = x @ fc_w.T + fc_b (MFMA, in-place on hb: grid.x==1 so safe)
    {
        dim3 g(1, (N + 127) / 128);
        gemm_mfma<0, 0><<<g, 256, 0, stream>>>(hb, DIM, fc_wb, DIM, fc_b,
                                               hb, DIM, 0, N, DIM);
    }
    // 2) su / sv
    attn_scores_kernel<<<(N + 3) / 4, 256, 0, stream>>>(hb, au_w, au_b, av_w, su, sv, N);
    // 3) CSR build
    degree_count_kernel<<<(E + 255) / 256, 256, 0, stream>>>(src, dst, out_deg, in_cnt, E);
    scan_kernel<<<1, 1024, 0, stream>>>(in_cnt, rowstart);
    fill_csr_kernel<<<(E + 255) / 256, 256, 0, stream>>>(src, dst, rowstart, cursor, esrc, E);
    // 4) gather aggregation -> full bf16 cat (no atomics)
    gather_aggregate_kernel<<<(N + 3) / 4, 256, 0, stream>>>(
        rowstart, esrc, hb, su, sv, out_deg, cat, N);

    // 5) FFN per chunk: f = gelu(cat@w1.T+b1) -> out = f@w2.T+b2
    for (int c = 0; c < N / CH; ++c) {
        int c0 = c * CH;
        {
            dim3 g(HID / 128, (CH + 127) / 128);
            gemm_mfma<0, 1><<<g, 256, 0, stream>>>(cat + (size_t)c0 * 512, 512,
                                                   w1b, 512, b1,
                                                   fbuf, HID, 0, CH, 512);
        }
        {
            dim3 g(DIM / 128, (CH + 127) / 128);
            gemm_mfma<1, 0><<<g, 256, 0, stream>>>(fbuf, HID, w2b, HID, b2,
                                                   out, DIM, c0, CH, 512);
        }
    }
}

// Round 8
// 582.805 us; speedup vs baseline: 15.1933x; 1.2296x over previous
//
#include <hip/hip_runtime.h>
#include <hip/hip_bf16.h>

#define NNODES 50000
#define NEDGES 800000
#define DIM 128
#define NH 8
#define HID 512
#define DCAP 64              // per-node edge cache depth (max in-deg ~45 @ Poisson(16))

typedef unsigned short ushort_t;
typedef __attribute__((ext_vector_type(8))) short bf16x8;
typedef __attribute__((ext_vector_type(4))) float f32x4;

// ---------------------------------------------------------------------------
__global__ __launch_bounds__(256) void f32_to_bf16_kernel(
    const float* __restrict__ in, ushort_t* __restrict__ out, int n)
{
    int i = blockIdx.x * 256 + threadIdx.x;
    if (i >= n) return;
    ((__hip_bfloat16*)out)[i] = __float2bfloat16(in[i]);
}

// all three weight matrices in one dispatch (16384 + 262144 + 65536 = 344064)
__global__ __launch_bounds__(256) void convert_weights_kernel(
    const float* __restrict__ fc_w, const float* __restrict__ w1,
    const float* __restrict__ w2,
    ushort_t* __restrict__ fc_wb, ushort_t* __restrict__ w1b,
    ushort_t* __restrict__ w2b)
{
    int i = blockIdx.x * 256 + threadIdx.x;
    if (i < 16384)
        ((__hip_bfloat16*)fc_wb)[i] = __float2bfloat16(fc_w[i]);
    else if (i < 278528)
        ((__hip_bfloat16*)w1b)[i - 16384] = __float2bfloat16(w1[i - 16384]);
    else if (i < 344064)
        ((__hip_bfloat16*)w2b)[i - 278528] = __float2bfloat16(w2[i - 278528]);
}

// ---------------------------------------------------------------------------
// MFMA NT GEMM (verified r5): C = act(A@B^T + bias)
// ---------------------------------------------------------------------------
template<int OUTF32, int ACT>
__global__ __launch_bounds__(256) void gemm_mfma(
    const ushort_t* A, int lda,
    const ushort_t* __restrict__ B, int ldb,
    const float* __restrict__ bias,
    void* C, int ldc, int row0,
    int M, int K)
{
    constexpr int BM = 128, BN = 128, BK = 64, PAD = 8;
    __shared__ ushort_t As[BM][BK + PAD];
    __shared__ ushort_t Bs[BN][BK + PAD];

    const int t    = threadIdx.x;
    const int bm   = blockIdx.y * BM;
    const int bn   = blockIdx.x * BN;
    const int wid  = t >> 6, lane = t & 63;
    const int wrow = wid >> 1, wcol = wid & 1;
    const int qd   = lane >> 4, l16 = lane & 15;

    f32x4 acc[4][4];
#pragma unroll
    for (int i = 0; i < 4; ++i)
#pragma unroll
        for (int j = 0; j < 4; ++j) acc[i][j] = (f32x4){0.f, 0.f, 0.f, 0.f};

    for (int k0 = 0; k0 < K; k0 += BK) {
#pragma unroll
        for (int i = 0; i < 4; ++i) {
            int v = t + i * 256;
            int r = v >> 3, c8 = (v & 7) * 8;
            uint4 val = make_uint4(0u, 0u, 0u, 0u);
            int gr = bm + r;
            if (gr < M) val = *(const uint4*)(A + (size_t)gr * lda + k0 + c8);
            *(uint4*)(&As[r][c8]) = val;
        }
#pragma unroll
        for (int i = 0; i < 4; ++i) {
            int v = t + i * 256;
            int r = v >> 3, c8 = (v & 7) * 8;
            *(uint4*)(&Bs[r][c8]) = *(const uint4*)(B + (size_t)(bn + r) * ldb + k0 + c8);
        }
        __syncthreads();

#pragma unroll
        for (int ks = 0; ks < 2; ++ks) {
            bf16x8 af[4], bfr[4];
#pragma unroll
            for (int mi = 0; mi < 4; ++mi)
                af[mi] = *(const bf16x8*)(&As[wrow * 64 + mi * 16 + l16][ks * 32 + qd * 8]);
#pragma unroll
            for (int ni = 0; ni < 4; ++ni)
                bfr[ni] = *(const bf16x8*)(&Bs[wcol * 64 + ni * 16 + l16][ks * 32 + qd * 8]);
#pragma unroll
            for (int mi = 0; mi < 4; ++mi)
#pragma unroll
                for (int ni = 0; ni < 4; ++ni)
                    acc[mi][ni] = __builtin_amdgcn_mfma_f32_16x16x32_bf16(
                        af[mi], bfr[ni], acc[mi][ni], 0, 0, 0);
        }
        __syncthreads();
    }

#pragma unroll
    for (int mi = 0; mi < 4; ++mi) {
#pragma unroll
        for (int r = 0; r < 4; ++r) {
            int lrow = wrow * 64 + mi * 16 + qd * 4 + r;
            int grow = bm + lrow;
            if (grow >= M) continue;
#pragma unroll
            for (int ni = 0; ni < 4; ++ni) {
                int gc = bn + wcol * 64 + ni * 16 + l16;
                float v = acc[mi][ni][r] + bias[gc];
                if (ACT == 1) v = 0.5f * v * (1.f + erff(v * 0.70710678118654752f));
                size_t off = (size_t)(row0 + grow) * ldc + gc;
                if (OUTF32) ((float*)C)[off] = v;
                else ((__hip_bfloat16*)C)[off] = __float2bfloat16(v);
            }
        }
    }
}

// ---------------------------------------------------------------------------
__global__ __launch_bounds__(256) void attn_scores_kernel(
    const ushort_t* __restrict__ hb,
    const float* __restrict__ au_w, const float* __restrict__ au_b,
    const float* __restrict__ av_w,
    float* __restrict__ su, float* __restrict__ sv, int N)
{
    const int wave = threadIdx.x >> 6;
    const int lane = threadIdx.x & 63;
    const int n = blockIdx.x * 4 + wave;
    if (n >= N) return;

    const float h0 = __bfloat162float(((const __hip_bfloat16*)hb)[(size_t)n * DIM + lane]);
    const float h1 = __bfloat162float(((const __hip_bfloat16*)hb)[(size_t)n * DIM + 64 + lane]);

    float au[NH], av[NH];
#pragma unroll
    for (int hh = 0; hh < NH; ++hh) {
        au[hh] = h0 * au_w[hh * DIM + lane] + h1 * au_w[hh * DIM + 64 + lane];
        av[hh] = h0 * av_w[hh * DIM + lane] + h1 * av_w[hh * DIM + 64 + lane];
    }
#pragma unroll
    for (int off = 32; off >= 1; off >>= 1) {
#pragma unroll
        for (int hh = 0; hh < NH; ++hh) {
            au[hh] += __shfl_down(au[hh], off, 64);
            av[hh] += __shfl_down(av[hh], off, 64);
        }
    }
    if (lane == 0) {
#pragma unroll
        for (int hh = 0; hh < NH; ++hh) {
            su[(size_t)n * NH + hh] = au[hh] + au_b[hh];
            sv[(size_t)n * NH + hh] = av[hh];
        }
    }
}

// ---------------------------------------------------------------------------
// CSR build: count (+float out_deg), single-block scan, fill.
// ---------------------------------------------------------------------------
__global__ __launch_bounds__(256) void degree_count_kernel(
    const int* __restrict__ src, const int* __restrict__ dst,
    float* __restrict__ out_deg, int* __restrict__ in_cnt, int E)
{
    int e = blockIdx.x * 256 + threadIdx.x;
    if (e >= E) return;
    unsafeAtomicAdd(&out_deg[src[e]], 1.f);
    atomicAdd(&in_cnt[dst[e]], 1);
}

__global__ __launch_bounds__(1024) void scan_kernel(
    const int* __restrict__ cnt, int* __restrict__ rowstart)
{
    __shared__ int ssum[1024];
    const int tid = threadIdx.x;
    const int C = (NNODES + 1023) / 1024;   // 49
    int base = tid * C;
    int s = 0;
    for (int i = 0; i < C; ++i) {
        int idx = base + i;
        if (idx < NNODES) s += cnt[idx];
    }
    ssum[tid] = s;
    __syncthreads();
    for (int off = 1; off < 1024; off <<= 1) {
        int v = (tid >= off) ? ssum[tid - off] : 0;
        __syncthreads();
        ssum[tid] += v;
        __syncthreads();
    }
    int run = (tid == 0) ? 0 : ssum[tid - 1];
    for (int i = 0; i < C; ++i) {
        int idx = base + i;
        if (idx < NNODES) { rowstart[idx] = run; run += cnt[idx]; }
    }
    if (tid == 0) rowstart[NNODES] = NEDGES;
}

__global__ __launch_bounds__(256) void fill_csr_kernel(
    const int* __restrict__ src, const int* __restrict__ dst,
    const int* __restrict__ rowstart, int* __restrict__ cursor,
    int* __restrict__ esrc, int E)
{
    int e = blockIdx.x * 256 + threadIdx.x;
    if (e >= E) return;
    int d = dst[e];
    int pos = rowstart[d] + atomicAdd(&cursor[d], 1);
    esrc[pos] = src[e];
}

// ---------------------------------------------------------------------------
// Gather-aggregate with per-wave LDS p-cache. One wave per dst node; lane
// owns dims {lane, lane+64}, head hh=lane&7. Pass A computes exp once per
// (edge,head) and caches it + per-edge norm in LDS; pass B is pure FMA.
// ---------------------------------------------------------------------------
__global__ __launch_bounds__(256) void gather_aggregate_kernel(
    const int* __restrict__ rowstart, const int* __restrict__ esrc,
    const ushort_t* __restrict__ hb,
    const float* __restrict__ su, const float* __restrict__ sv,
    const float* __restrict__ out_deg,
    ushort_t* __restrict__ cat, int N)
{
    __shared__ float pc[4][DCAP][NH];   // 8 KB
    __shared__ float nc[4][DCAP];       // 1 KB

    const int wave = threadIdx.x >> 6;
    const int lane = threadIdx.x & 63;
    const int n = blockIdx.x * 4 + wave;
    const bool active = (n < N);

    int e0 = 0, deg = 0;
    float svh = 0.f, od_d = 1.f;
    const int hh = lane & 7;
    if (active) {
        e0  = rowstart[n];
        deg = rowstart[n + 1] - e0;
        svh = sv[(size_t)n * NH + hh];
        od_d = out_deg[n];
    }

    // pass A: 8 edge-groups in parallel; cache ex and norm, reduce den
    float den = 0.f;
    for (int j = lane >> 3; j < deg; j += 8) {
        int s = esrc[e0 + j];
        float sc = su[(size_t)s * NH + hh] + svh;
        sc = sc < 0.f ? 0.2f * sc : sc;
        float ex = expf(sc);
        den += ex;
        if (j < DCAP) {
            pc[wave][j][hh] = ex;
            if (hh == 0) nc[wave][j] = rsqrtf(out_deg[s] * od_d);
        }
    }
    den += __shfl_xor(den, 8, 64);
    den += __shfl_xor(den, 16, 64);
    den += __shfl_xor(den, 32, 64);
    float rden = (den > 0.f) ? 1.f / den : 0.f;

    __syncthreads();

    // pass B: pure gather + FMA (p/norm from LDS; fallback recompute j>=DCAP)
    float m0 = 0.f, m1 = 0.f, s0 = 0.f, s1 = 0.f, n0 = 0.f, n1 = 0.f;
    for (int j = 0; j < deg; ++j) {
        int s = esrc[e0 + j];
        float p, norm;
        if (j < DCAP) {
            p = pc[wave][j][hh] * rden;
            norm = nc[wave][j];
        } else {
            float sc = su[(size_t)s * NH + hh] + svh;
            sc = sc < 0.f ? 0.2f * sc : sc;
            p = expf(sc) * rden;
            norm = rsqrtf(out_deg[s] * od_d);
        }
        float hs0 = __bfloat162float(((const __hip_bfloat16*)hb)[(size_t)s * DIM + lane]);
        float hs1 = __bfloat162float(((const __hip_bfloat16*)hb)[(size_t)s * DIM + 64 + lane]);
        m0 += hs0 * p;    m1 += hs1 * p;
        s0 += hs0;        s1 += hs1;
        n0 += hs0 * norm; n1 += hs1 * norm;
    }

    if (active) {
        float inv = 1.f / fmaxf((float)deg, 1.f);
        __hip_bfloat16* row = (__hip_bfloat16*)cat + (size_t)n * 512;
        row[lane]       = ((const __hip_bfloat16*)hb)[(size_t)n * DIM + lane];
        row[64 + lane]  = ((const __hip_bfloat16*)hb)[(size_t)n * DIM + 64 + lane];
        row[128 + lane] = __float2bfloat16(m0);
        row[192 + lane] = __float2bfloat16(m1);
        row[256 + lane] = __float2bfloat16(s0 * inv);
        row[320 + lane] = __float2bfloat16(s1 * inv);
        row[384 + lane] = __float2bfloat16(n0);
        row[448 + lane] = __float2bfloat16(n1);
    }
}

// ---------------------------------------------------------------------------
extern "C" void kernel_launch(void* const* d_in, const int* in_sizes, int n_in,
                              void* d_out, int out_size, void* d_ws, size_t ws_size,
                              hipStream_t stream)
{
    const float* x    = (const float*)d_in[0];
    const int*   src  = (const int*)d_in[1];
    const int*   dst  = (const int*)d_in[2];
    const float* fc_w = (const float*)d_in[3];
    const float* fc_b = (const float*)d_in[4];
    const float* au_w = (const float*)d_in[5];
    const float* au_b = (const float*)d_in[6];
    const float* av_w = (const float*)d_in[7];
    const float* w1   = (const float*)d_in[8];
    const float* b1   = (const float*)d_in[9];
    const float* w2   = (const float*)d_in[10];
    const float* b2   = (const float*)d_in[11];
    float* out = (float*)d_out;

    const int N = NNODES, E = NEDGES;

    // ws layout (no trailing backslashes in comments -- r6 lesson)
    char* w = (char*)d_ws;
    ushort_t* fc_wb = (ushort_t*)w;  w += (size_t)DIM * DIM * 2;
    ushort_t* w1b   = (ushort_t*)w;  w += (size_t)HID * 512 * 2;
    ushort_t* w2b   = (ushort_t*)w;  w += (size_t)DIM * HID * 2;
    ushort_t* hb    = (ushort_t*)w;  w += (size_t)N * DIM * 2;       // 12.8 MB
    ushort_t* cat   = (ushort_t*)w;  w += (size_t)N * 512 * 2;       // 51.2 MB
    float* su       = (float*)w;     w += (size_t)N * NH * 4;
    float* sv       = (float*)w;     w += (size_t)N * NH * 4;
    float* out_deg  = (float*)w;     w += (size_t)N * 4;             // zeroed (1/3)
    int*   in_cnt   = (int*)w;       w += (size_t)N * 4;             // zeroed (2/3)
    int*   cursor   = (int*)w;       w += (size_t)N * 4;             // zeroed (3/3)
    int*   rowstart = (int*)w;       w += (size_t)(N + 16) * 4;
    int*   esrc     = (int*)w;       w += (size_t)E * 4;             // 3.2 MB
    size_t base_bytes = (size_t)(w - (char*)d_ws);                   // ~71.9 MB
    ushort_t* fbuf  = (ushort_t*)w;

    // FFN chunk size: un-chunked if the workspace can hold full f (51.2 MB);
    // ws_size is constant across calls, so this branch is graph-deterministic.
    const int CHR = (ws_size >= base_bytes + (size_t)N * 512 * 2 + 1024) ? N : 12500;

    (void)hipMemsetAsync(out_deg, 0, (size_t)N * 3 * 4, stream);

    // convert weights (single dispatch) + x to bf16
    convert_weights_kernel<<<1344, 256, 0, stream>>>(fc_w, w1, w2, fc_wb, w1b, w2b);
    f32_to_bf16_kernel<<<(N * DIM + 255) / 256, 256, 0, stream>>>(x, hb, N * DIM);

    // 1) h = x @ fc_w.T + fc_b (MFMA, in-place on hb: grid.x==1 so safe)
    {
        dim3 g(1, (N + 127) / 128);
        gemm_mfma<0, 0><<<g, 256, 0, stream>>>(hb, DIM, fc_wb, DIM, fc_b,
                                               hb, DIM, 0, N, DIM);
    }
    // 2) su / sv
    attn_scores_kernel<<<(N + 3) / 4, 256, 0, stream>>>(hb, au_w, au_b, av_w, su, sv, N);
    // 3) CSR build
    degree_count_kernel<<<(E + 255) / 256, 256, 0, stream>>>(src, dst, out_deg, in_cnt, E);
    scan_kernel<<<1, 1024, 0, stream>>>(in_cnt, rowstart);
    fill_csr_kernel<<<(E + 255) / 256, 256, 0, stream>>>(src, dst, rowstart, cursor, esrc, E);
    // 4) gather aggregation -> full bf16 cat (no atomics)
    gather_aggregate_kernel<<<(N + 3) / 4, 256, 0, stream>>>(
        rowstart, esrc, hb, su, sv, out_deg, cat, N);

    // 5) FFN: f = gelu(cat@w1.T+b1) -> out = f@w2.T+b2
    for (int c0 = 0; c0 < N; c0 += CHR) {
        int Mc = (c0 + CHR <= N) ? CHR : N - c0;
        {
            dim3 g(HID / 128, (Mc + 127) / 128);
            gemm_mfma<0, 1><<<g, 256, 0, stream>>>(cat + (size_t)c0 * 512, 512,
                                                   w1b, 512, b1,
                                                   fbuf, HID, 0, Mc, 512);
        }
        {
            dim3 g(DIM / 128, (Mc + 127) / 128);
            gemm_mfma<1, 0><<<g, 256, 0, stream>>>(fbuf, HID, w2b, HID, b2,
                                                   out, DIM, c0, Mc, 512);
        }
    }
}

// Round 9
// 554.992 us; speedup vs baseline: 15.9547x; 1.0501x over previous
//
#include <hip/hip_runtime.h>
#include <hip/hip_bf16.h>

#define NNODES 50000
#define NEDGES 800000
#define DIM 128
#define NH 8
#define HID 512
#define DCAP 64              // per-node edge cache depth (max in-deg ~45 @ Poisson(16))

typedef unsigned short ushort_t;
typedef __attribute__((ext_vector_type(8))) short bf16x8;
typedef __attribute__((ext_vector_type(4))) float f32x4;

// ---------------------------------------------------------------------------
// all three weight matrices in one dispatch (16384 + 262144 + 65536 = 344064)
__global__ __launch_bounds__(256) void convert_weights_kernel(
    const float* __restrict__ fc_w, const float* __restrict__ w1,
    const float* __restrict__ w2,
    ushort_t* __restrict__ fc_wb, ushort_t* __restrict__ w1b,
    ushort_t* __restrict__ w2b)
{
    int i = blockIdx.x * 256 + threadIdx.x;
    if (i < 16384)
        ((__hip_bfloat16*)fc_wb)[i] = __float2bfloat16(fc_w[i]);
    else if (i < 278528)
        ((__hip_bfloat16*)w1b)[i - 16384] = __float2bfloat16(w1[i - 16384]);
    else if (i < 344064)
        ((__hip_bfloat16*)w2b)[i - 278528] = __float2bfloat16(w2[i - 278528]);
}

// ---------------------------------------------------------------------------
// MFMA NT GEMM: C = act(A@B^T + bias).  BK=32 (20.5 KB LDS -> 3 blocks/CU at
// the 3-waves/SIMD register cap; r8's BK=64/36.9KB capped at 2 blocks/CU and
// was barrier-latency-bound at MfmaUtil 10%).
// AF32: A is fp32, converted to bf16 during staging (fuses x-conversion).
// OUTF32: C fp32 (else bf16).  ACT=1: exact gelu.
// ---------------------------------------------------------------------------
template<int AF32, int OUTF32, int ACT>
__global__ __launch_bounds__(256, 3) void gemm_mfma(
    const void* A, int lda,
    const ushort_t* __restrict__ B, int ldb,
    const float* __restrict__ bias,
    void* C, int ldc, int row0,
    int M, int K)
{
    constexpr int BM = 128, BN = 128, BK = 32, PAD = 8;
    __shared__ ushort_t As[BM][BK + PAD];
    __shared__ ushort_t Bs[BN][BK + PAD];

    const int t    = threadIdx.x;
    const int bm   = blockIdx.y * BM;
    const int bn   = blockIdx.x * BN;
    const int wid  = t >> 6, lane = t & 63;
    const int wrow = wid >> 1, wcol = wid & 1;
    const int qd   = lane >> 4, l16 = lane & 15;

    f32x4 acc[4][4];
#pragma unroll
    for (int i = 0; i < 4; ++i)
#pragma unroll
        for (int j = 0; j < 4; ++j) acc[i][j] = (f32x4){0.f, 0.f, 0.f, 0.f};

    for (int k0 = 0; k0 < K; k0 += BK) {
        // stage A tile: 128x32 ushorts = 512 uint4s, 2 per thread
#pragma unroll
        for (int i = 0; i < 2; ++i) {
            int v = t + i * 256;
            int r = v >> 2, c8 = (v & 3) * 8;
            int gr = bm + r;
            if (AF32) {
                float4 f0 = make_float4(0.f, 0.f, 0.f, 0.f), f1 = f0;
                if (gr < M) {
                    const float* ap = (const float*)A + (size_t)gr * lda + k0 + c8;
                    f0 = *(const float4*)ap;
                    f1 = *(const float4*)(ap + 4);
                }
                __hip_bfloat16* dst = (__hip_bfloat16*)&As[r][c8];
                dst[0] = __float2bfloat16(f0.x); dst[1] = __float2bfloat16(f0.y);
                dst[2] = __float2bfloat16(f0.z); dst[3] = __float2bfloat16(f0.w);
                dst[4] = __float2bfloat16(f1.x); dst[5] = __float2bfloat16(f1.y);
                dst[6] = __float2bfloat16(f1.z); dst[7] = __float2bfloat16(f1.w);
            } else {
                uint4 val = make_uint4(0u, 0u, 0u, 0u);
                if (gr < M) val = *(const uint4*)((const ushort_t*)A + (size_t)gr * lda + k0 + c8);
                *(uint4*)(&As[r][c8]) = val;
            }
        }
        // stage B tile (rows of B are always a multiple of 128 here)
#pragma unroll
        for (int i = 0; i < 2; ++i) {
            int v = t + i * 256;
            int r = v >> 2, c8 = (v & 3) * 8;
            *(uint4*)(&Bs[r][c8]) = *(const uint4*)(B + (size_t)(bn + r) * ldb + k0 + c8);
        }
        __syncthreads();

        bf16x8 af[4], bfr[4];
#pragma unroll
        for (int mi = 0; mi < 4; ++mi)
            af[mi] = *(const bf16x8*)(&As[wrow * 64 + mi * 16 + l16][qd * 8]);
#pragma unroll
        for (int ni = 0; ni < 4; ++ni)
            bfr[ni] = *(const bf16x8*)(&Bs[wcol * 64 + ni * 16 + l16][qd * 8]);
#pragma unroll
        for (int mi = 0; mi < 4; ++mi)
#pragma unroll
            for (int ni = 0; ni < 4; ++ni)
                acc[mi][ni] = __builtin_amdgcn_mfma_f32_16x16x32_bf16(
                    af[mi], bfr[ni], acc[mi][ni], 0, 0, 0);
        __syncthreads();
    }

    // epilogue: C/D layout col=lane&15, row=(lane>>4)*4+reg  [m89/m91]
#pragma unroll
    for (int mi = 0; mi < 4; ++mi) {
#pragma unroll
        for (int r = 0; r < 4; ++r) {
            int lrow = wrow * 64 + mi * 16 + qd * 4 + r;
            int grow = bm + lrow;
            if (grow >= M) continue;
#pragma unroll
            for (int ni = 0; ni < 4; ++ni) {
                int gc = bn + wcol * 64 + ni * 16 + l16;
                float v = acc[mi][ni][r] + bias[gc];
                if (ACT == 1) v = 0.5f * v * (1.f + erff(v * 0.70710678118654752f));
                size_t off = (size_t)(row0 + grow) * ldc + gc;
                if (OUTF32) ((float*)C)[off] = v;
                else ((__hip_bfloat16*)C)[off] = __float2bfloat16(v);
            }
        }
    }
}

// ---------------------------------------------------------------------------
__global__ __launch_bounds__(256) void attn_scores_kernel(
    const ushort_t* __restrict__ hb,
    const float* __restrict__ au_w, const float* __restrict__ au_b,
    const float* __restrict__ av_w,
    float* __restrict__ su, float* __restrict__ sv, int N)
{
    const int wave = threadIdx.x >> 6;
    const int lane = threadIdx.x & 63;
    const int n = blockIdx.x * 4 + wave;
    if (n >= N) return;

    const float h0 = __bfloat162float(((const __hip_bfloat16*)hb)[(size_t)n * DIM + lane]);
    const float h1 = __bfloat162float(((const __hip_bfloat16*)hb)[(size_t)n * DIM + 64 + lane]);

    float au[NH], av[NH];
#pragma unroll
    for (int hh = 0; hh < NH; ++hh) {
        au[hh] = h0 * au_w[hh * DIM + lane] + h1 * au_w[hh * DIM + 64 + lane];
        av[hh] = h0 * av_w[hh * DIM + lane] + h1 * av_w[hh * DIM + 64 + lane];
    }
#pragma unroll
    for (int off = 32; off >= 1; off >>= 1) {
#pragma unroll
        for (int hh = 0; hh < NH; ++hh) {
            au[hh] += __shfl_down(au[hh], off, 64);
            av[hh] += __shfl_down(av[hh], off, 64);
        }
    }
    if (lane == 0) {
#pragma unroll
        for (int hh = 0; hh < NH; ++hh) {
            su[(size_t)n * NH + hh] = au[hh] + au_b[hh];
            sv[(size_t)n * NH + hh] = av[hh];
        }
    }
}

// ---------------------------------------------------------------------------
// CSR build: count (+float out_deg), single-block scan, fill.
// ---------------------------------------------------------------------------
__global__ __launch_bounds__(256) void degree_count_kernel(
    const int* __restrict__ src, const int* __restrict__ dst,
    float* __restrict__ out_deg, int* __restrict__ in_cnt, int E)
{
    int e = blockIdx.x * 256 + threadIdx.x;
    if (e >= E) return;
    unsafeAtomicAdd(&out_deg[src[e]], 1.f);
    atomicAdd(&in_cnt[dst[e]], 1);
}

__global__ __launch_bounds__(1024) void scan_kernel(
    const int* __restrict__ cnt, int* __restrict__ rowstart)
{
    __shared__ int ssum[1024];
    const int tid = threadIdx.x;
    const int C = (NNODES + 1023) / 1024;   // 49
    int base = tid * C;
    int s = 0;
    for (int i = 0; i < C; ++i) {
        int idx = base + i;
        if (idx < NNODES) s += cnt[idx];
    }
    ssum[tid] = s;
    __syncthreads();
    for (int off = 1; off < 1024; off <<= 1) {
        int v = (tid >= off) ? ssum[tid - off] : 0;
        __syncthreads();
        ssum[tid] += v;
        __syncthreads();
    }
    int run = (tid == 0) ? 0 : ssum[tid - 1];
    for (int i = 0; i < C; ++i) {
        int idx = base + i;
        if (idx < NNODES) { rowstart[idx] = run; run += cnt[idx]; }
    }
    if (tid == 0) rowstart[NNODES] = NEDGES;
}

__global__ __launch_bounds__(256) void fill_csr_kernel(
    const int* __restrict__ src, const int* __restrict__ dst,
    const int* __restrict__ rowstart, int* __restrict__ cursor,
    int* __restrict__ esrc, int E)
{
    int e = blockIdx.x * 256 + threadIdx.x;
    if (e >= E) return;
    int d = dst[e];
    int pos = rowstart[d] + atomicAdd(&cursor[d], 1);
    esrc[pos] = src[e];
}

// ---------------------------------------------------------------------------
// Gather-aggregate with per-wave LDS p-cache (verified r8). One wave per dst
// node; lane owns dims {lane, lane+64}, head hh=lane&7.
// ---------------------------------------------------------------------------
__global__ __launch_bounds__(256) void gather_aggregate_kernel(
    const int* __restrict__ rowstart, const int* __restrict__ esrc,
    const ushort_t* __restrict__ hb,
    const float* __restrict__ su, const float* __restrict__ sv,
    const float* __restrict__ out_deg,
    ushort_t* __restrict__ cat, int N)
{
    __shared__ float pc[4][DCAP][NH];   // 8 KB
    __shared__ float nc[4][DCAP];       // 1 KB

    const int wave = threadIdx.x >> 6;
    const int lane = threadIdx.x & 63;
    const int n = blockIdx.x * 4 + wave;
    const bool active = (n < N);

    int e0 = 0, deg = 0;
    float svh = 0.f, od_d = 1.f;
    const int hh = lane & 7;
    if (active) {
        e0  = rowstart[n];
        deg = rowstart[n + 1] - e0;
        svh = sv[(size_t)n * NH + hh];
        od_d = out_deg[n];
    }

    // pass A: 8 edge-groups in parallel; cache ex and norm, reduce den
    float den = 0.f;
    for (int j = lane >> 3; j < deg; j += 8) {
        int s = esrc[e0 + j];
        float sc = su[(size_t)s * NH + hh] + svh;
        sc = sc < 0.f ? 0.2f * sc : sc;
        float ex = expf(sc);
        den += ex;
        if (j < DCAP) {
            pc[wave][j][hh] = ex;
            if (hh == 0) nc[wave][j] = rsqrtf(out_deg[s] * od_d);
        }
    }
    den += __shfl_xor(den, 8, 64);
    den += __shfl_xor(den, 16, 64);
    den += __shfl_xor(den, 32, 64);
    float rden = (den > 0.f) ? 1.f / den : 0.f;

    __syncthreads();

    // pass B: pure gather + FMA (p/norm from LDS; fallback recompute j>=DCAP)
    float m0 = 0.f, m1 = 0.f, s0 = 0.f, s1 = 0.f, n0 = 0.f, n1 = 0.f;
    for (int j = 0; j < deg; ++j) {
        int s = esrc[e0 + j];
        float p, norm;
        if (j < DCAP) {
            p = pc[wave][j][hh] * rden;
            norm = nc[wave][j];
        } else {
            float sc = su[(size_t)s * NH + hh] + svh;
            sc = sc < 0.f ? 0.2f * sc : sc;
            p = expf(sc) * rden;
            norm = rsqrtf(out_deg[s] * od_d);
        }
        float hs0 = __bfloat162float(((const __hip_bfloat16*)hb)[(size_t)s * DIM + lane]);
        float hs1 = __bfloat162float(((const __hip_bfloat16*)hb)[(size_t)s * DIM + 64 + lane]);
        m0 += hs0 * p;    m1 += hs1 * p;
        s0 += hs0;        s1 += hs1;
        n0 += hs0 * norm; n1 += hs1 * norm;
    }

    if (active) {
        float inv = 1.f / fmaxf((float)deg, 1.f);
        __hip_bfloat16* row = (__hip_bfloat16*)cat + (size_t)n * 512;
        row[lane]       = ((const __hip_bfloat16*)hb)[(size_t)n * DIM + lane];
        row[64 + lane]  = ((const __hip_bfloat16*)hb)[(size_t)n * DIM + 64 + lane];
        row[128 + lane] = __float2bfloat16(m0);
        row[192 + lane] = __float2bfloat16(m1);
        row[256 + lane] = __float2bfloat16(s0 * inv);
        row[320 + lane] = __float2bfloat16(s1 * inv);
        row[384 + lane] = __float2bfloat16(n0);
        row[448 + lane] = __float2bfloat16(n1);
    }
}

// ---------------------------------------------------------------------------
extern "C" void kernel_launch(void* const* d_in, const int* in_sizes, int n_in,
                              void* d_out, int out_size, void* d_ws, size_t ws_size,
                              hipStream_t stream)
{
    const float* x    = (const float*)d_in[0];
    const int*   src  = (const int*)d_in[1];
    const int*   dst  = (const int*)d_in[2];
    const float* fc_w = (const float*)d_in[3];
    const float* fc_b = (const float*)d_in[4];
    const float* au_w = (const float*)d_in[5];
    const float* au_b = (const float*)d_in[6];
    const float* av_w = (const float*)d_in[7];
    const float* w1   = (const float*)d_in[8];
    const float* b1   = (const float*)d_in[9];
    const float* w2   = (const float*)d_in[10];
    const float* b2   = (const float*)d_in[11];
    float* out = (float*)d_out;

    const int N = NNODES, E = NEDGES;

    // ws layout (no trailing backslashes in comments -- r6 lesson)
    char* w = (char*)d_ws;
    ushort_t* fc_wb = (ushort_t*)w;  w += (size_t)DIM * DIM * 2;
    ushort_t* w1b   = (ushort_t*)w;  w += (size_t)HID * 512 * 2;
    ushort_t* w2b   = (ushort_t*)w;  w += (size_t)DIM * HID * 2;
    ushort_t* hb    = (ushort_t*)w;  w += (size_t)N * DIM * 2;       // 12.8 MB
    ushort_t* cat   = (ushort_t*)w;  w += (size_t)N * 512 * 2;       // 51.2 MB
    float* su       = (float*)w;     w += (size_t)N * NH * 4;
    float* sv       = (float*)w;     w += (size_t)N * NH * 4;
    float* out_deg  = (float*)w;     w += (size_t)N * 4;             // zeroed (1/3)
    int*   in_cnt   = (int*)w;       w += (size_t)N * 4;             // zeroed (2/3)
    int*   cursor   = (int*)w;       w += (size_t)N * 4;             // zeroed (3/3)
    int*   rowstart = (int*)w;       w += (size_t)(N + 16) * 4;
    int*   esrc     = (int*)w;       w += (size_t)E * 4;             // 3.2 MB
    size_t base_bytes = (size_t)(w - (char*)d_ws);                   // ~71.9 MB
    ushort_t* fbuf  = (ushort_t*)w;

    // FFN chunk size: un-chunked when ws holds full f (r8 confirmed it does)
    const int CHR = (ws_size >= base_bytes + (size_t)N * 512 * 2 + 1024) ? N : 12500;

    (void)hipMemsetAsync(out_deg, 0, (size_t)N * 3 * 4, stream);

    // convert weights (single dispatch); x converts inside h-GEMM staging now
    convert_weights_kernel<<<1344, 256, 0, stream>>>(fc_w, w1, w2, fc_wb, w1b, w2b);

    // 1) h = x @ fc_w.T + fc_b  (AF32 staging converts x fp32->bf16 in-flight)
    {
        dim3 g(1, (N + 127) / 128);
        gemm_mfma<1, 0, 0><<<g, 256, 0, stream>>>(x, DIM, fc_wb, DIM, fc_b,
                                                  hb, DIM, 0, N, DIM);
    }
    // 2) su / sv
    attn_scores_kernel<<<(N + 3) / 4, 256, 0, stream>>>(hb, au_w, au_b, av_w, su, sv, N);
    // 3) CSR build
    degree_count_kernel<<<(E + 255) / 256, 256, 0, stream>>>(src, dst, out_deg, in_cnt, E);
    scan_kernel<<<1, 1024, 0, stream>>>(in_cnt, rowstart);
    fill_csr_kernel<<<(E + 255) / 256, 256, 0, stream>>>(src, dst, rowstart, cursor, esrc, E);
    // 4) gather aggregation -> full bf16 cat (no atomics)
    gather_aggregate_kernel<<<(N + 3) / 4, 256, 0, stream>>>(
        rowstart, esrc, hb, su, sv, out_deg, cat, N);

    // 5) FFN: f = gelu(cat@w1.T+b1) -> out = f@w2.T+b2
    for (int c0 = 0; c0 < N; c0 += CHR) {
        int Mc = (c0 + CHR <= N) ? CHR : N - c0;
        {
            dim3 g(HID / 128, (Mc + 127) / 128);
            gemm_mfma<0, 0, 1><<<g, 256, 0, stream>>>(cat + (size_t)c0 * 512, 512,
                                                      w1b, 512, b1,
                                                      fbuf, HID, 0, Mc, 512);
        }
        {
            dim3 g(DIM / 128, (Mc + 127) / 128);
            gemm_mfma<0, 1, 0><<<g, 256, 0, stream>>>(fbuf, HID, w2b, HID, b2,
                                                      out, DIM, c0, Mc, 512);
        }
    }
}

// Round 11
// 472.465 us; speedup vs baseline: 18.7415x; 1.1747x over previous
//
#include <hip/hip_runtime.h>
#include <hip/hip_bf16.h>

#define NNODES 50000
#define NEDGES 800000
#define DIM 128
#define NH 8
#define HID 512
#define DCAP 64              // per-node edge cache depth (max in-deg ~45 @ Poisson(16))
#define NB 196               // scan blocks: ceil(50000/256)

typedef unsigned short ushort_t;
typedef unsigned int uint_t;
typedef __attribute__((ext_vector_type(8))) short bf16x8;
typedef __attribute__((ext_vector_type(4))) float f32x4;

// ---------------------------------------------------------------------------
// all three weight matrices in one dispatch (16384 + 262144 + 65536 = 344064)
__global__ __launch_bounds__(256) void convert_weights_kernel(
    const float* __restrict__ fc_w, const float* __restrict__ w1,
    const float* __restrict__ w2,
    ushort_t* __restrict__ fc_wb, ushort_t* __restrict__ w1b,
    ushort_t* __restrict__ w2b)
{
    int i = blockIdx.x * 256 + threadIdx.x;
    if (i < 16384)
        ((__hip_bfloat16*)fc_wb)[i] = __float2bfloat16(fc_w[i]);
    else if (i < 278528)
        ((__hip_bfloat16*)w1b)[i - 16384] = __float2bfloat16(w1[i - 16384]);
    else if (i < 344064)
        ((__hip_bfloat16*)w2b)[i - 278528] = __float2bfloat16(w2[i - 278528]);
}

// ---------------------------------------------------------------------------
// MFMA NT GEMM (verified r9): C = act(A@B^T + bias). BK=32, 3 blocks/CU.
// ---------------------------------------------------------------------------
template<int AF32, int OUTF32, int ACT>
__global__ __launch_bounds__(256, 3) void gemm_mfma(
    const void* A, int lda,
    const ushort_t* __restrict__ B, int ldb,
    const float* __restrict__ bias,
    void* C, int ldc, int row0,
    int M, int K)
{
    constexpr int BM = 128, BN = 128, BK = 32, PAD = 8;
    __shared__ ushort_t As[BM][BK + PAD];
    __shared__ ushort_t Bs[BN][BK + PAD];

    const int t    = threadIdx.x;
    const int bm   = blockIdx.y * BM;
    const int bn   = blockIdx.x * BN;
    const int wid  = t >> 6, lane = t & 63;
    const int wrow = wid >> 1, wcol = wid & 1;
    const int qd   = lane >> 4, l16 = lane & 15;

    f32x4 acc[4][4];
#pragma unroll
    for (int i = 0; i < 4; ++i)
#pragma unroll
        for (int j = 0; j < 4; ++j) acc[i][j] = (f32x4){0.f, 0.f, 0.f, 0.f};

    for (int k0 = 0; k0 < K; k0 += BK) {
#pragma unroll
        for (int i = 0; i < 2; ++i) {
            int v = t + i * 256;
            int r = v >> 2, c8 = (v & 3) * 8;
            int gr = bm + r;
            if (AF32) {
                float4 f0 = make_float4(0.f, 0.f, 0.f, 0.f), f1 = f0;
                if (gr < M) {
                    const float* ap = (const float*)A + (size_t)gr * lda + k0 + c8;
                    f0 = *(const float4*)ap;
                    f1 = *(const float4*)(ap + 4);
                }
                __hip_bfloat16* dstp = (__hip_bfloat16*)&As[r][c8];
                dstp[0] = __float2bfloat16(f0.x); dstp[1] = __float2bfloat16(f0.y);
                dstp[2] = __float2bfloat16(f0.z); dstp[3] = __float2bfloat16(f0.w);
                dstp[4] = __float2bfloat16(f1.x); dstp[5] = __float2bfloat16(f1.y);
                dstp[6] = __float2bfloat16(f1.z); dstp[7] = __float2bfloat16(f1.w);
            } else {
                uint4 val = make_uint4(0u, 0u, 0u, 0u);
                if (gr < M) val = *(const uint4*)((const ushort_t*)A + (size_t)gr * lda + k0 + c8);
                *(uint4*)(&As[r][c8]) = val;
            }
        }
#pragma unroll
        for (int i = 0; i < 2; ++i) {
            int v = t + i * 256;
            int r = v >> 2, c8 = (v & 3) * 8;
            *(uint4*)(&Bs[r][c8]) = *(const uint4*)(B + (size_t)(bn + r) * ldb + k0 + c8);
        }
        __syncthreads();

        bf16x8 af[4], bfr[4];
#pragma unroll
        for (int mi = 0; mi < 4; ++mi)
            af[mi] = *(const bf16x8*)(&As[wrow * 64 + mi * 16 + l16][qd * 8]);
#pragma unroll
        for (int ni = 0; ni < 4; ++ni)
            bfr[ni] = *(const bf16x8*)(&Bs[wcol * 64 + ni * 16 + l16][qd * 8]);
#pragma unroll
        for (int mi = 0; mi < 4; ++mi)
#pragma unroll
            for (int ni = 0; ni < 4; ++ni)
                acc[mi][ni] = __builtin_amdgcn_mfma_f32_16x16x32_bf16(
                    af[mi], bfr[ni], acc[mi][ni], 0, 0, 0);
        __syncthreads();
    }

#pragma unroll
    for (int mi = 0; mi < 4; ++mi) {
#pragma unroll
        for (int r = 0; r < 4; ++r) {
            int lrow = wrow * 64 + mi * 16 + qd * 4 + r;
            int grow = bm + lrow;
            if (grow >= M) continue;
#pragma unroll
            for (int ni = 0; ni < 4; ++ni) {
                int gc = bn + wcol * 64 + ni * 16 + l16;
                float v = acc[mi][ni][r] + bias[gc];
                if (ACT == 1) v = 0.5f * v * (1.f + erff(v * 0.70710678118654752f));
                size_t off = (size_t)(row0 + grow) * ldc + gc;
                if (OUTF32) ((float*)C)[off] = v;
                else ((__hip_bfloat16*)C)[off] = __float2bfloat16(v);
            }
        }
    }
}

// ---------------------------------------------------------------------------
__global__ __launch_bounds__(256) void attn_scores_kernel(
    const ushort_t* __restrict__ hb,
    const float* __restrict__ au_w, const float* __restrict__ au_b,
    const float* __restrict__ av_w,
    float* __restrict__ su, float* __restrict__ sv, int N)
{
    const int wave = threadIdx.x >> 6;
    const int lane = threadIdx.x & 63;
    const int n = blockIdx.x * 4 + wave;
    if (n >= N) return;

    const float h0 = __bfloat162float(((const __hip_bfloat16*)hb)[(size_t)n * DIM + lane]);
    const float h1 = __bfloat162float(((const __hip_bfloat16*)hb)[(size_t)n * DIM + 64 + lane]);

    float au[NH], av[NH];
#pragma unroll
    for (int hh = 0; hh < NH; ++hh) {
        au[hh] = h0 * au_w[hh * DIM + lane] + h1 * au_w[hh * DIM + 64 + lane];
        av[hh] = h0 * av_w[hh * DIM + lane] + h1 * av_w[hh * DIM + 64 + lane];
    }
#pragma unroll
    for (int off = 32; off >= 1; off >>= 1) {
#pragma unroll
        for (int hh = 0; hh < NH; ++hh) {
            au[hh] += __shfl_down(au[hh], off, 64);
            av[hh] += __shfl_down(av[hh], off, 64);
        }
    }
    if (lane == 0) {
#pragma unroll
        for (int hh = 0; hh < NH; ++hh) {
            su[(size_t)n * NH + hh] = au[hh] + au_b[hh];
            sv[(size_t)n * NH + hh] = av[hh];
        }
    }
}

// ---------------------------------------------------------------------------
// degree count + multi-block scan (kept from r10: analysis-clean; r9's
// single-block scan was 92.7 us of one-CU latency).
// ---------------------------------------------------------------------------
__global__ __launch_bounds__(256) void degree_count_kernel(
    const int* __restrict__ src, const int* __restrict__ dst,
    float* __restrict__ out_deg, int* __restrict__ in_cnt, int E)
{
    int e = blockIdx.x * 256 + threadIdx.x;
    if (e >= E) return;
    unsafeAtomicAdd(&out_deg[src[e]], 1.f);
    atomicAdd(&in_cnt[dst[e]], 1);
}

__global__ __launch_bounds__(256) void block_sum_kernel(
    const int* __restrict__ cnt, int* __restrict__ bsum)
{
    const int lane = threadIdx.x & 63, wid = threadIdx.x >> 6;
    int i = blockIdx.x * 256 + threadIdx.x;
    int v = (i < NNODES) ? cnt[i] : 0;
#pragma unroll
    for (int off = 32; off >= 1; off >>= 1) v += __shfl_down(v, off, 64);
    __shared__ int ws_[4];
    if (lane == 0) ws_[wid] = v;
    __syncthreads();
    if (threadIdx.x == 0) bsum[blockIdx.x] = ws_[0] + ws_[1] + ws_[2] + ws_[3];
}

__global__ __launch_bounds__(256) void block_scan_kernel(
    const int* __restrict__ bsum, int* __restrict__ boff)
{
    __shared__ int sb[256];
    const int t = threadIdx.x;
    int v = (t < NB) ? bsum[t] : 0;
    sb[t] = v;
    __syncthreads();
    for (int off = 1; off < 256; off <<= 1) {
        int u = (t >= off) ? sb[t - off] : 0;
        __syncthreads();
        sb[t] += u;
        __syncthreads();
    }
    if (t < NB) boff[t] = (t == 0) ? 0 : sb[t - 1];
}

__global__ __launch_bounds__(256) void final_scan_kernel(
    const int* __restrict__ cnt, const int* __restrict__ boff,
    int* __restrict__ rowstart)
{
    __shared__ int sb[256];
    const int t = threadIdx.x;
    const int b = blockIdx.x;
    int i = b * 256 + t;
    int v = (i < NNODES) ? cnt[i] : 0;
    sb[t] = v;
    __syncthreads();
    for (int off = 1; off < 256; off <<= 1) {
        int u = (t >= off) ? sb[t - off] : 0;
        __syncthreads();
        sb[t] += u;
        __syncthreads();
    }
    if (i < NNODES) rowstart[i] = boff[b] + sb[t] - v;   // exclusive
    if (b == 0 && t == 0) rowstart[NNODES] = NEDGES;
}

__global__ __launch_bounds__(256) void fill_csr_kernel(
    const int* __restrict__ src, const int* __restrict__ dst,
    const int* __restrict__ rowstart, int* __restrict__ cursor,
    int* __restrict__ esrc, int E)
{
    int e = blockIdx.x * 256 + threadIdx.x;
    if (e >= E) return;
    int d = dst[e];
    int pos = rowstart[d] + atomicAdd(&cursor[d], 1);
    esrc[pos] = src[e];
}

// ---------------------------------------------------------------------------
// Gather-aggregate: EXACT r9 version (verified absmax 0.0078). r10's v3
// rewrite regressed accuracy to 0.0596 — reverted wholesale for bisection.
// One wave per dst node; lane owns dims {lane, lane+64}, head hh=lane&7.
// ---------------------------------------------------------------------------
__global__ __launch_bounds__(256) void gather_aggregate_kernel(
    const int* __restrict__ rowstart, const int* __restrict__ esrc,
    const ushort_t* __restrict__ hb,
    const float* __restrict__ su, const float* __restrict__ sv,
    const float* __restrict__ out_deg,
    ushort_t* __restrict__ cat, int N)
{
    __shared__ float pc[4][DCAP][NH];   // 8 KB
    __shared__ float nc[4][DCAP];       // 1 KB

    const int wave = threadIdx.x >> 6;
    const int lane = threadIdx.x & 63;
    const int n = blockIdx.x * 4 + wave;
    const bool active = (n < N);

    int e0 = 0, deg = 0;
    float svh = 0.f, od_d = 1.f;
    const int hh = lane & 7;
    if (active) {
        e0  = rowstart[n];
        deg = rowstart[n + 1] - e0;
        svh = sv[(size_t)n * NH + hh];
        od_d = out_deg[n];
    }

    // pass A: 8 edge-groups in parallel; cache ex and norm, reduce den
    float den = 0.f;
    for (int j = lane >> 3; j < deg; j += 8) {
        int s = esrc[e0 + j];
        float sc = su[(size_t)s * NH + hh] + svh;
        sc = sc < 0.f ? 0.2f * sc : sc;
        float ex = expf(sc);
        den += ex;
        if (j < DCAP) {
            pc[wave][j][hh] = ex;
            if (hh == 0) nc[wave][j] = rsqrtf(out_deg[s] * od_d);
        }
    }
    den += __shfl_xor(den, 8, 64);
    den += __shfl_xor(den, 16, 64);
    den += __shfl_xor(den, 32, 64);
    float rden = (den > 0.f) ? 1.f / den : 0.f;

    __syncthreads();

    // pass B: pure gather + FMA (p/norm from LDS; fallback recompute j>=DCAP)
    float m0 = 0.f, m1 = 0.f, s0 = 0.f, s1 = 0.f, n0 = 0.f, n1 = 0.f;
    for (int j = 0; j < deg; ++j) {
        int s = esrc[e0 + j];
        float p, norm;
        if (j < DCAP) {
            p = pc[wave][j][hh] * rden;
            norm = nc[wave][j];
        } else {
            float sc = su[(size_t)s * NH + hh] + svh;
            sc = sc < 0.f ? 0.2f * sc : sc;
            p = expf(sc) * rden;
            norm = rsqrtf(out_deg[s] * od_d);
        }
        float hs0 = __bfloat162float(((const __hip_bfloat16*)hb)[(size_t)s * DIM + lane]);
        float hs1 = __bfloat162float(((const __hip_bfloat16*)hb)[(size_t)s * DIM + 64 + lane]);
        m0 += hs0 * p;    m1 += hs1 * p;
        s0 += hs0;        s1 += hs1;
        n0 += hs0 * norm; n1 += hs1 * norm;
    }

    if (active) {
        float inv = 1.f / fmaxf((float)deg, 1.f);
        __hip_bfloat16* row = (__hip_bfloat16*)cat + (size_t)n * 512;
        row[lane]       = ((const __hip_bfloat16*)hb)[(size_t)n * DIM + lane];
        row[64 + lane]  = ((const __hip_bfloat16*)hb)[(size_t)n * DIM + 64 + lane];
        row[128 + lane] = __float2bfloat16(m0);
        row[192 + lane] = __float2bfloat16(m1);
        row[256 + lane] = __float2bfloat16(s0 * inv);
        row[320 + lane] = __float2bfloat16(s1 * inv);
        row[384 + lane] = __float2bfloat16(n0);
        row[448 + lane] = __float2bfloat16(n1);
    }
}

// ---------------------------------------------------------------------------
extern "C" void kernel_launch(void* const* d_in, const int* in_sizes, int n_in,
                              void* d_out, int out_size, void* d_ws, size_t ws_size,
                              hipStream_t stream)
{
    const float* x    = (const float*)d_in[0];
    const int*   src  = (const int*)d_in[1];
    const int*   dst  = (const int*)d_in[2];
    const float* fc_w = (const float*)d_in[3];
    const float* fc_b = (const float*)d_in[4];
    const float* au_w = (const float*)d_in[5];
    const float* au_b = (const float*)d_in[6];
    const float* av_w = (const float*)d_in[7];
    const float* w1   = (const float*)d_in[8];
    const float* b1   = (const float*)d_in[9];
    const float* w2   = (const float*)d_in[10];
    const float* b2   = (const float*)d_in[11];
    float* out = (float*)d_out;

    const int N = NNODES, E = NEDGES;

    // ws layout (no trailing backslashes in comments -- r6 lesson)
    char* w = (char*)d_ws;
    ushort_t* fc_wb = (ushort_t*)w;  w += (size_t)DIM * DIM * 2;
    ushort_t* w1b   = (ushort_t*)w;  w += (size_t)HID * 512 * 2;
    ushort_t* w2b   = (ushort_t*)w;  w += (size_t)DIM * HID * 2;
    ushort_t* hb    = (ushort_t*)w;  w += (size_t)N * DIM * 2;       // 12.8 MB
    ushort_t* cat   = (ushort_t*)w;  w += (size_t)N * 512 * 2;       // 51.2 MB
    float* su       = (float*)w;     w += (size_t)N * NH * 4;
    float* sv       = (float*)w;     w += (size_t)N * NH * 4;
    float* out_deg  = (float*)w;     w += (size_t)N * 4;             // zeroed (1/3)
    int*   in_cnt   = (int*)w;       w += (size_t)N * 4;             // zeroed (2/3)
    int*   cursor   = (int*)w;       w += (size_t)N * 4;             // zeroed (3/3)
    int*   rowstart = (int*)w;       w += (size_t)(N + 16) * 4;
    int*   bsum     = (int*)w;       w += (size_t)256 * 4;
    int*   boff     = (int*)w;       w += (size_t)256 * 4;
    int*   esrc     = (int*)w;       w += (size_t)E * 4;             // 3.2 MB
    size_t base_bytes = (size_t)(w - (char*)d_ws);                   // ~72 MB
    ushort_t* fbuf  = (ushort_t*)w;

    const int CHR = (ws_size >= base_bytes + (size_t)N * 512 * 2 + 1024) ? N : 12500;

    (void)hipMemsetAsync(out_deg, 0, (size_t)N * 3 * 4, stream);

    convert_weights_kernel<<<1344, 256, 0, stream>>>(fc_w, w1, w2, fc_wb, w1b, w2b);

    // 1) h = x @ fc_w.T + fc_b  (AF32 staging converts x fp32->bf16 in-flight)
    {
        dim3 g(1, (N + 127) / 128);
        gemm_mfma<1, 0, 0><<<g, 256, 0, stream>>>(x, DIM, fc_wb, DIM, fc_b,
                                                  hb, DIM, 0, N, DIM);
    }
    // 2) su / sv
    attn_scores_kernel<<<(N + 3) / 4, 256, 0, stream>>>(hb, au_w, au_b, av_w, su, sv, N);
    // 3) degrees + CSR (multi-block scan)
    degree_count_kernel<<<(E + 255) / 256, 256, 0, stream>>>(src, dst, out_deg, in_cnt, E);
    block_sum_kernel<<<NB, 256, 0, stream>>>(in_cnt, bsum);
    block_scan_kernel<<<1, 256, 0, stream>>>(bsum, boff);
    final_scan_kernel<<<NB, 256, 0, stream>>>(in_cnt, boff, rowstart);
    fill_csr_kernel<<<(E + 255) / 256, 256, 0, stream>>>(src, dst, rowstart, cursor, esrc, E);
    // 4) gather aggregation -> full bf16 cat (no atomics)
    gather_aggregate_kernel<<<(N + 3) / 4, 256, 0, stream>>>(
        rowstart, esrc, hb, su, sv, out_deg, cat, N);

    // 5) FFN: f = gelu(cat@w1.T+b1) -> out = f@w2.T+b2
    for (int c0 = 0; c0 < N; c0 += CHR) {
        int Mc = (c0 + CHR <= N) ? CHR : N - c0;
        {
            dim3 g(HID / 128, (Mc + 127) / 128);
            gemm_mfma<0, 0, 1><<<g, 256, 0, stream>>>(cat + (size_t)c0 * 512, 512,
                                                      w1b, 512, b1,
                                                      fbuf, HID, 0, Mc, 512);
        }
        {
            dim3 g(DIM / 128, (Mc + 127) / 128);
            gemm_mfma<0, 1, 0><<<g, 256, 0, stream>>>(fbuf, HID, w2b, HID, b2,
                                                      out, DIM, c0, Mc, 512);
        }
    }
}